// Round 3
// baseline (3791.172 us; speedup 1.0000x reference)
//
#include <hip/hip_runtime.h>

using u16 = unsigned short;
using u32 = unsigned int;

#define NS 8192
#define NQ 16384
#define SZ 64
#define STEPS 10
#define TS 128
#define NT (NS / TS)
#define L2E 1.44269504088896340736f

typedef __attribute__((ext_vector_type(8))) _Float16 f16x8;
typedef __attribute__((ext_vector_type(4))) float f32x4;

static __device__ __forceinline__ float ex2(float x) { float r; asm("v_exp_f32 %0, %1" : "=v"(r) : "v"(x)); return r; }
static __device__ __forceinline__ float rcp_(float x) { float r; asm("v_rcp_f32 %0, %1" : "=v"(r) : "v"(x)); return r; }

static __device__ __forceinline__ u16 hbits(_Float16 h) { union { _Float16 h; u16 u; } c; c.h = h; return c.u; }
// pack two floats as f16 pair (RNE converts)
static __device__ __forceinline__ u32 pk2(float lo, float hi) {
    return (u32)hbits((_Float16)lo) | ((u32)hbits((_Float16)hi) << 16);
}
static __device__ __forceinline__ f32x4 MMH(f16x8 a, f16x8 b, f32x4 c) {
    return __builtin_amdgcn_mfma_f32_16x16x32_f16(a, b, c, 0, 0, 0);
}
static __device__ __forceinline__ f16x8 LD(const u16* p) { return *(const f16x8*)p; }
static __device__ __forceinline__ float sig(float x) { return rcp_(1.f + ex2(-L2E * x)); }
static __device__ __forceinline__ float tanh_(float x) {
    float e = ex2(-2.f * L2E * x);
    return (1.f - e) * rcp_(1.f + e);
}
static __device__ __forceinline__ void lds_fence() {
    asm volatile("s_waitcnt lgkmcnt(0)" ::: "memory");
    __builtin_amdgcn_sched_barrier(0);
}

// ---------------- prep: f16 hi/lo splits + tiled transpose + bias sum ----------------
__global__ void prep_kernel(const float* __restrict__ sup,
                            const float* __restrict__ Wih,
                            const float* __restrict__ Whh,
                            const float* __restrict__ bih,
                            const float* __restrict__ bhh,
                            u16* __restrict__ supH, u16* __restrict__ supL,
                            u16* __restrict__ supT,
                            u16* __restrict__ WiH, u16* __restrict__ WiL,
                            u16* __restrict__ WhH, u16* __restrict__ WhL,
                            float* __restrict__ bs) {
    int i = blockIdx.x * 256 + threadIdx.x;
    if (i < NS * SZ) {
        float v = sup[i];
        _Float16 hi = (_Float16)v;
        _Float16 lo = (_Float16)(v - (float)hi);
        supH[i] = hbits(hi);
        supL[i] = hbits(lo);
        int s = i >> 6, d = i & 63;
        // tiled transpose (single f16 is enough for PV): supT[tile][d][s_local]
        supT[(s >> 7) * (SZ * TS) + d * TS + (s & 127)] = hbits(hi);
    }
    if (i < 4 * SZ * SZ) {
        float a = Wih[i]; _Float16 ah = (_Float16)a;
        WiH[i] = hbits(ah); WiL[i] = hbits((_Float16)(a - (float)ah));
        float b = Whh[i]; _Float16 bh = (_Float16)b;
        WhH[i] = hbits(bh); WhL[i] = hbits((_Float16)(b - (float)bh));
    }
    if (i < 4 * SZ) bs[i] = bih[i] + bhh[i];
}

// ---------------- main fused kernel: 1 wave / block, 16 query rows / wave ----------------
// Lane roles: q = lane&15 (query column in all swapped MFMAs), g = lane>>4.
// Per-lane d-slot mapping (O accum, c, h_hat, queries, gates): slot t <-> d = 4g + (t&3) + 16*(t>>2)
// A/B fragment layout (16x16x32): row/col = lane&15, k = (lane>>4)*8 + j (8 contiguous)
// C/D layout: col = lane&15, row = (lane>>4)*4 + reg
__global__ __launch_bounds__(64) void attlstm_kernel(
    const float* __restrict__ queries,
    const u16* __restrict__ supH, const u16* __restrict__ supL,
    const u16* __restrict__ supT,
    const u16* __restrict__ WiH, const u16* __restrict__ WiL,
    const u16* __restrict__ WhH, const u16* __restrict__ WhL,
    const float* __restrict__ bsum,
    float* __restrict__ out) {
    __shared__ __align__(16) u16 qbh[16 * 64], qbl[16 * 64];   // queries hi/lo, [q][d]
    __shared__ __align__(16) u16 hbh_[16 * 64], hbl_[16 * 64]; // h hi/lo
    __shared__ __align__(16) u16 hrh[16 * 64], hrl[16 * 64];   // h+readout hi/lo
    __shared__ __align__(16) u32 P_lds[16 * 64];               // 16 q-rows x 256B, XOR-swizzled
    __shared__ __align__(16) float bs_lds[256];

    const int l = threadIdx.x;
    const int q = l & 15;
    const int g = l >> 4;
    const int qrow = blockIdx.x * 16 + q;

    *(f32x4*)&bs_lds[l * 4] = *(const f32x4*)&bsum[l * 4];

    float qv[16], hh[16], cc[16];
#pragma unroll
    for (int s4 = 0; s4 < 4; ++s4) {
        f32x4 v = *(const f32x4*)&queries[qrow * SZ + 16 * s4 + 4 * g];
#pragma unroll
        for (int jj = 0; jj < 4; ++jj) {
            qv[4 * s4 + jj] = v[jj];
            hh[4 * s4 + jj] = 0.f;
            cc[4 * s4 + jj] = 0.f;
        }
        _Float16 c0 = (_Float16)v[0], c1 = (_Float16)v[1], c2 = (_Float16)v[2], c3 = (_Float16)v[3];
        uint2 whi, wlo;
        whi.x = (u32)hbits(c0) | ((u32)hbits(c1) << 16);
        whi.y = (u32)hbits(c2) | ((u32)hbits(c3) << 16);
        wlo.x = pk2(v[0] - (float)c0, v[1] - (float)c1);
        wlo.y = pk2(v[2] - (float)c2, v[3] - (float)c3);
        *(uint2*)&qbh[q * 64 + 16 * s4 + 4 * g] = whi;
        *(uint2*)&qbl[q * 64 + 16 * s4 + 4 * g] = wlo;
    }
    lds_fence();
    const f16x8 qfh0 = LD(&qbh[q * 64 + 8 * g]), qfh1 = LD(&qbh[q * 64 + 32 + 8 * g]);
    const f16x8 qfl0 = LD(&qbl[q * 64 + 8 * g]), qfl1 = LD(&qbl[q * 64 + 32 + 8 * g]);

#pragma unroll 1
    for (int step = 0; step < STEPS; ++step) {
        // ---- h = h_hat + queries, split hi/lo -> LDS ----
#pragma unroll
        for (int s4 = 0; s4 < 4; ++s4) {
            float h0 = hh[4 * s4 + 0] + qv[4 * s4 + 0];
            float h1 = hh[4 * s4 + 1] + qv[4 * s4 + 1];
            float h2 = hh[4 * s4 + 2] + qv[4 * s4 + 2];
            float h3 = hh[4 * s4 + 3] + qv[4 * s4 + 3];
            _Float16 a0 = (_Float16)h0, a1 = (_Float16)h1, a2 = (_Float16)h2, a3 = (_Float16)h3;
            uint2 whi, wlo;
            whi.x = (u32)hbits(a0) | ((u32)hbits(a1) << 16);
            whi.y = (u32)hbits(a2) | ((u32)hbits(a3) << 16);
            wlo.x = pk2(h0 - (float)a0, h1 - (float)a1);
            wlo.y = pk2(h2 - (float)a2, h3 - (float)a3);
            *(uint2*)&hbh_[q * 64 + 16 * s4 + 4 * g] = whi;
            *(uint2*)&hbl_[q * 64 + 16 * s4 + 4 * g] = wlo;
        }
        lds_fence();
        const f16x8 bh0 = LD(&hbh_[q * 64 + 8 * g]), bh1 = LD(&hbh_[q * 64 + 32 + 8 * g]);
        const f16x8 bl0 = LD(&hbl_[q * 64 + 8 * g]), bl1 = LD(&hbl_[q * 64 + 32 + 8 * g]);

        float m = -1e30f, lsum = 0.f;
        f32x4 Oa[4] = {{0, 0, 0, 0}, {0, 0, 0, 0}, {0, 0, 0, 0}, {0, 0, 0, 0}};

#pragma unroll 1
        for (int t = 0; t < NT; ++t) {
            // ---- S^T = sup_tile . h (3-product split): lane holds S[16sub+4g+jj][q] ----
            const u16* psH = supH + (t * TS + q) * SZ + 8 * g;
            const u16* psL = supL + (t * TS + q) * SZ + 8 * g;
            f32x4 sv[8];
#pragma unroll
            for (int sub = 0; sub < 8; ++sub) {
                const u16* pH = psH + sub * 16 * SZ;
                const u16* pL = psL + sub * 16 * SZ;
                f16x8 aH0 = LD(pH), aH1 = LD(pH + 32);
                f32x4 a = {0, 0, 0, 0};
                a = MMH(aH0, bh0, a); a = MMH(aH1, bh1, a);
                a = MMH(aH0, bl0, a); a = MMH(aH1, bl1, a);
                a = MMH(LD(pL), bh0, a); a = MMH(LD(pL + 32), bh1, a);
                sv[sub] = a;
            }
            // ---- online softmax (row q lane-local; reduce over 4 lane-groups) ----
            float tm = -1e30f;
#pragma unroll
            for (int sub = 0; sub < 8; ++sub)
                tm = fmaxf(tm, fmaxf(fmaxf(sv[sub][0], sv[sub][1]), fmaxf(sv[sub][2], sv[sub][3])));
            tm = fmaxf(tm, __shfl_xor(tm, 16));
            tm = fmaxf(tm, __shfl_xor(tm, 32));
            float mn = fmaxf(m, tm);
            float sc = ex2((m - mn) * L2E);
            m = mn;
            float mL = mn * L2E;
            lsum *= sc;
            Oa[0] *= sc; Oa[1] *= sc; Oa[2] *= sc; Oa[3] *= sc;
            // ---- P = exp(S - m) -> f16 -> swizzled LDS ----
#pragma unroll
            for (int sub = 0; sub < 8; ++sub) {
                float p0 = ex2(sv[sub][0] * L2E - mL);
                float p1 = ex2(sv[sub][1] * L2E - mL);
                float p2 = ex2(sv[sub][2] * L2E - mL);
                float p3 = ex2(sv[sub][3] * L2E - mL);
                lsum += (p0 + p1) + (p2 + p3);
                uint2 w; w.x = pk2(p0, p1); w.y = pk2(p2, p3);
                u32 sb = (u32)(8 * g + 32 * sub) ^ ((u32)(q & 7) << 4);
                *(uint2*)((char*)P_lds + q * 256 + sb) = w;
            }
            lds_fence();
            // ---- O^T += supT_tile . P : lane accumulates readout[16dsub+4g+jj][q] ----
            const u16* pt = supT + t * (SZ * TS) + q * TS + 8 * g;
#pragma unroll
            for (int c4 = 0; c4 < 4; ++c4) {
                u32 sb = (u32)(64 * c4 + 16 * g) ^ ((u32)(q & 7) << 4);
                f16x8 pb = *(const f16x8*)((char*)P_lds + q * 256 + sb);
                Oa[0] = MMH(LD(pt + 0 * 16 * TS + 32 * c4), pb, Oa[0]);
                Oa[1] = MMH(LD(pt + 1 * 16 * TS + 32 * c4), pb, Oa[1]);
                Oa[2] = MMH(LD(pt + 2 * 16 * TS + 32 * c4), pb, Oa[2]);
                Oa[3] = MMH(LD(pt + 3 * 16 * TS + 32 * c4), pb, Oa[3]);
            }
        }
        lsum += __shfl_xor(lsum, 16);
        lsum += __shfl_xor(lsum, 32);
        float inv = rcp_(lsum);

        // ---- hr = h + readout, split hi/lo -> LDS ----
#pragma unroll
        for (int s4 = 0; s4 < 4; ++s4) {
            float r0 = hh[4 * s4 + 0] + qv[4 * s4 + 0] + Oa[s4][0] * inv;
            float r1 = hh[4 * s4 + 1] + qv[4 * s4 + 1] + Oa[s4][1] * inv;
            float r2 = hh[4 * s4 + 2] + qv[4 * s4 + 2] + Oa[s4][2] * inv;
            float r3 = hh[4 * s4 + 3] + qv[4 * s4 + 3] + Oa[s4][3] * inv;
            _Float16 a0 = (_Float16)r0, a1 = (_Float16)r1, a2 = (_Float16)r2, a3 = (_Float16)r3;
            uint2 whi, wlo;
            whi.x = (u32)hbits(a0) | ((u32)hbits(a1) << 16);
            whi.y = (u32)hbits(a2) | ((u32)hbits(a3) << 16);
            wlo.x = pk2(r0 - (float)a0, r1 - (float)a1);
            wlo.y = pk2(r2 - (float)a2, r3 - (float)a3);
            *(uint2*)&hrh[q * 64 + 16 * s4 + 4 * g] = whi;
            *(uint2*)&hrl[q * 64 + 16 * s4 + 4 * g] = wlo;
        }
        lds_fence();
        const f16x8 rh0 = LD(&hrh[q * 64 + 8 * g]), rh1 = LD(&hrh[q * 64 + 32 + 8 * g]);
        const f16x8 rl0 = LD(&hrl[q * 64 + 8 * g]), rl1 = LD(&hrl[q * 64 + 32 + 8 * g]);

        // ---- gates^T = Wstack . [queries; hr] + bias (3-product splits); LSTM elementwise ----
#pragma unroll
        for (int s4 = 0; s4 < 4; ++s4) {
            f32x4 ga[4];
#pragma unroll
            for (int ch = 0; ch < 4; ++ch) {  // 0=i 1=f 2=g 3=o
                int u_ = 4 * ch + s4;
                f32x4 a = *(const f32x4*)&bs_lds[16 * u_ + 4 * g];
                const u16* wiH = WiH + (16 * u_ + q) * SZ + 8 * g;
                const u16* wiL = WiL + (16 * u_ + q) * SZ + 8 * g;
                const u16* whH = WhH + (16 * u_ + q) * SZ + 8 * g;
                const u16* whL = WhL + (16 * u_ + q) * SZ + 8 * g;
                f16x8 w0 = LD(wiH), w1 = LD(wiH + 32);
                a = MMH(w0, qfh0, a); a = MMH(w1, qfh1, a);
                a = MMH(w0, qfl0, a); a = MMH(w1, qfl1, a);
                a = MMH(LD(wiL), qfh0, a); a = MMH(LD(wiL + 32), qfh1, a);
                f16x8 v0 = LD(whH), v1 = LD(whH + 32);
                a = MMH(v0, rh0, a); a = MMH(v1, rh1, a);
                a = MMH(v0, rl0, a); a = MMH(v1, rl1, a);
                a = MMH(LD(whL), rh0, a); a = MMH(LD(whL + 32), rh1, a);
                ga[ch] = a;
            }
#pragma unroll
            for (int jj = 0; jj < 4; ++jj) {
                int tt = 4 * s4 + jj;
                float gi = sig(ga[0][jj]);
                float gf = sig(ga[1][jj]);
                float gg = tanh_(ga[2][jj]);
                float go = sig(ga[3][jj]);
                float cn = gf * cc[tt] + gi * gg;
                cc[tt] = cn;
                hh[tt] = go * tanh_(cn);
            }
        }
    }

    // ---- out = h_hat + queries ----
#pragma unroll
    for (int s4 = 0; s4 < 4; ++s4) {
        f32x4 v;
#pragma unroll
        for (int jj = 0; jj < 4; ++jj) v[jj] = hh[4 * s4 + jj] + qv[4 * s4 + jj];
        *(f32x4*)&out[qrow * SZ + 16 * s4 + 4 * g] = v;
    }
}

extern "C" void kernel_launch(void* const* d_in, const int* in_sizes, int n_in,
                              void* d_out, int out_size, void* d_ws, size_t ws_size,
                              hipStream_t stream) {
    const float* support = (const float*)d_in[0];
    const float* queries = (const float*)d_in[1];
    const float* W_ih = (const float*)d_in[2];
    const float* W_hh = (const float*)d_in[3];
    const float* b_ih = (const float*)d_in[4];
    const float* b_hh = (const float*)d_in[5];
    float* out = (float*)d_out;

    u16* supH = (u16*)d_ws;                    // 8192*64
    u16* supL = supH + NS * SZ;                // 8192*64
    u16* supT = supL + NS * SZ;                // 8192*64 (tiled transpose, hi)
    u16* WiH = supT + NS * SZ;                 // 256*64
    u16* WiL = WiH + 4 * SZ * SZ;
    u16* WhH = WiL + 4 * SZ * SZ;
    u16* WhL = WhH + 4 * SZ * SZ;
    float* bs = (float*)(WhL + 4 * SZ * SZ);   // 256

    prep_kernel<<<(NS * SZ) / 256, 256, 0, stream>>>(support, W_ih, W_hh, b_ih, b_hh,
                                                     supH, supL, supT, WiH, WiL, WhH, WhL, bs);
    attlstm_kernel<<<NQ / 16, 64, 0, stream>>>(queries, supH, supL, supT,
                                               WiH, WiL, WhH, WhL, bs, out);
}

// Round 4
// 1763.247 us; speedup vs baseline: 2.1501x; 2.1501x over previous
//
#include <hip/hip_runtime.h>

using u16 = unsigned short;
using u32 = unsigned int;

#define NS 8192
#define NQ 16384
#define SZ 64
#define STEPS 10
#define TS 64
#define NT (NS / TS)   // 128 tiles per step
#define L2E 1.44269504088896340736f

typedef __attribute__((ext_vector_type(8))) _Float16 f16x8;
typedef __attribute__((ext_vector_type(4))) float f32x4;

static __device__ __forceinline__ float ex2(float x) { float r; asm("v_exp_f32 %0, %1" : "=v"(r) : "v"(x)); return r; }
static __device__ __forceinline__ float rcp_(float x) { float r; asm("v_rcp_f32 %0, %1" : "=v"(r) : "v"(x)); return r; }

static __device__ __forceinline__ u16 hbits(_Float16 h) { union { _Float16 h; u16 u; } c; c.h = h; return c.u; }
static __device__ __forceinline__ u32 pk2(float lo, float hi) {
    return (u32)hbits((_Float16)lo) | ((u32)hbits((_Float16)hi) << 16);
}
static __device__ __forceinline__ f32x4 MMH(f16x8 a, f16x8 b, f32x4 c) {
    return __builtin_amdgcn_mfma_f32_16x16x32_f16(a, b, c, 0, 0, 0);
}
static __device__ __forceinline__ f16x8 LD(const void* p) { return *(const f16x8*)p; }
static __device__ __forceinline__ float sig(float x) { return rcp_(1.f + ex2(-L2E * x)); }
static __device__ __forceinline__ float tanh_(float x) {
    float e = ex2(-2.f * L2E * x);
    return (1.f - e) * rcp_(1.f + e);
}
// wave-local LDS write->read ordering (rule #18: lgkmcnt + sched_barrier)
static __device__ __forceinline__ void lds_fence() {
    asm volatile("s_waitcnt lgkmcnt(0)" ::: "memory");
    __builtin_amdgcn_sched_barrier(0);
}
// async global->LDS, 16B/lane, LDS dest wave-uniform (HW adds lane*16)
static __device__ __forceinline__ void gload16(const void* g, void* l) {
    __builtin_amdgcn_global_load_lds(
        (const __attribute__((address_space(1))) void*)g,
        (__attribute__((address_space(3))) void*)l, 16, 0, 0);
}

// ---------------- prep: f16 hi/lo splits + tiled transpose (TS=64) + bias sum ----------------
__global__ void prep_kernel(const float* __restrict__ sup,
                            const float* __restrict__ Wih,
                            const float* __restrict__ Whh,
                            const float* __restrict__ bih,
                            const float* __restrict__ bhh,
                            u16* __restrict__ supH, u16* __restrict__ supL,
                            u16* __restrict__ supT,
                            u16* __restrict__ WiH, u16* __restrict__ WiL,
                            u16* __restrict__ WhH, u16* __restrict__ WhL,
                            float* __restrict__ bs) {
    int i = blockIdx.x * 256 + threadIdx.x;
    if (i < NS * SZ) {
        float v = sup[i];
        _Float16 hi = (_Float16)v;
        _Float16 lo = (_Float16)(v - (float)hi);
        supH[i] = hbits(hi);
        supL[i] = hbits(lo);
        int s = i >> 6, d = i & 63;
        // tiled transpose: supT[tile][d][s_local], tile = 64 rows, contiguous 8KB
        supT[(s >> 6) * (SZ * TS) + d * TS + (s & 63)] = hbits(hi);
    }
    if (i < 4 * SZ * SZ) {
        float a = Wih[i]; _Float16 ah = (_Float16)a;
        WiH[i] = hbits(ah); WiL[i] = hbits((_Float16)(a - (float)ah));
        float b = Whh[i]; _Float16 bh = (_Float16)b;
        WhH[i] = hbits(bh); WhL[i] = hbits((_Float16)(b - (float)bh));
    }
    if (i < 4 * SZ) bs[i] = bih[i] + bhh[i];
}

// ---------------- main kernel: 4 waves/block, 64 queries/block, staged support ----------------
// Per-wave roles unchanged from round 3: q = lane&15, g = lane>>4.
// LDS tiles XOR-swizzled: within a 128B row, byte16-slot ^= (row&7). Staging writes
// linear LDS + pre-swizzled GLOBAL source (rule #21); reads apply the same XOR.
__global__ __launch_bounds__(256, 1) void attlstm_kernel(
    const float* __restrict__ queries,
    const u16* __restrict__ supH, const u16* __restrict__ supL,
    const u16* __restrict__ supT,
    const u16* __restrict__ WiH, const u16* __restrict__ WiL,
    const u16* __restrict__ WhH, const u16* __restrict__ WhL,
    const float* __restrict__ bsum,
    float* __restrict__ out) {
    // 48KB stage (2 bufs x {supH,supL,supT} x 8KB) + 8KB P + 1KB bias = 57KB
    __shared__ __align__(16) u16 stage[2][3][TS * SZ];
    __shared__ __align__(16) u32 P_lds[4][512];   // per-wave 16q x 64s f16, swizzled
    __shared__ __align__(16) float bs_lds[256];

    const int tid = threadIdx.x;
    const int wq = tid >> 6;          // wave id = query group
    const int l = tid & 63;
    const int q = l & 15;
    const int g = l >> 4;
    const int qrow = blockIdx.x * 64 + wq * 16 + q;
    const u32 swz = (u32)(q & 7) << 4;

    bs_lds[tid] = bsum[tid];

    // wave-private scratch slice (4KB) aliased into stage[0] — only used while
    // staging is quiescent (before prologue / after tile loop), barrier-separated.
    u16* slice = &stage[0][0][0] + wq * 2048;     // [0..1023]=hi, [1024..2047]=lo
    char* slc = (char*)slice;

    // staging source: per-lane pre-swizzled offset (elements) within a tile
    // chunk c = wq + 4j: array a=c>>3, s8=c&7; row = s8*8 + (l>>3); col16 = (l&7)^(l>>3)
    int srcoff[6]; const u16* abase[6]; u16* lbase[2][6];
#pragma unroll
    for (int j = 0; j < 6; ++j) {
        int c = wq + 4 * j;
        int a = c >> 3, s8 = c & 7;
        srcoff[j] = (s8 * 8 + (l >> 3)) * SZ + ((l & 7) ^ (l >> 3)) * 8;
        abase[j] = (a == 0) ? supH : (a == 1) ? supL : supT;
        lbase[0][j] = &stage[0][a][0] + s8 * 512;
        lbase[1][j] = &stage[1][a][0] + s8 * 512;
    }

    float qv[16], hh[16], cc[16];
#pragma unroll
    for (int s4 = 0; s4 < 4; ++s4) {
        f32x4 v = *(const f32x4*)&queries[qrow * SZ + 16 * s4 + 4 * g];
#pragma unroll
        for (int jj = 0; jj < 4; ++jj) {
            qv[4 * s4 + jj] = v[jj];
            hh[4 * s4 + jj] = 0.f;
            cc[4 * s4 + jj] = 0.f;
        }
        _Float16 c0 = (_Float16)v[0], c1 = (_Float16)v[1], c2 = (_Float16)v[2], c3 = (_Float16)v[3];
        uint2 whi, wlo;
        whi.x = (u32)hbits(c0) | ((u32)hbits(c1) << 16);
        whi.y = (u32)hbits(c2) | ((u32)hbits(c3) << 16);
        wlo.x = pk2(v[0] - (float)c0, v[1] - (float)c1);
        wlo.y = pk2(v[2] - (float)c2, v[3] - (float)c3);
        u32 b = q * 128 + ((32u * s4 + 8u * g) ^ swz);
        *(uint2*)(slc + b) = whi;
        *(uint2*)(slc + 2048 + b) = wlo;
    }
    lds_fence();
    const f16x8 qfh0 = LD(slc + q * 128 + ((16u * g) ^ swz));
    const f16x8 qfh1 = LD(slc + q * 128 + ((16u * g + 64u) ^ swz));
    const f16x8 qfl0 = LD(slc + 2048 + q * 128 + ((16u * g) ^ swz));
    const f16x8 qfl1 = LD(slc + 2048 + q * 128 + ((16u * g + 64u) ^ swz));

#pragma unroll 1
    for (int step = 0; step < STEPS; ++step) {
        // ---- h = h_hat + queries, hi/lo -> wave slice -> B-frags ----
#pragma unroll
        for (int s4 = 0; s4 < 4; ++s4) {
            float h0 = hh[4 * s4 + 0] + qv[4 * s4 + 0];
            float h1 = hh[4 * s4 + 1] + qv[4 * s4 + 1];
            float h2 = hh[4 * s4 + 2] + qv[4 * s4 + 2];
            float h3 = hh[4 * s4 + 3] + qv[4 * s4 + 3];
            _Float16 a0 = (_Float16)h0, a1 = (_Float16)h1, a2 = (_Float16)h2, a3 = (_Float16)h3;
            uint2 whi, wlo;
            whi.x = (u32)hbits(a0) | ((u32)hbits(a1) << 16);
            whi.y = (u32)hbits(a2) | ((u32)hbits(a3) << 16);
            wlo.x = pk2(h0 - (float)a0, h1 - (float)a1);
            wlo.y = pk2(h2 - (float)a2, h3 - (float)a3);
            u32 b = q * 128 + ((32u * s4 + 8u * g) ^ swz);
            *(uint2*)(slc + b) = whi;
            *(uint2*)(slc + 2048 + b) = wlo;
        }
        lds_fence();
        const f16x8 bh0 = LD(slc + q * 128 + ((16u * g) ^ swz));
        const f16x8 bh1 = LD(slc + q * 128 + ((16u * g + 64u) ^ swz));
        const f16x8 bl0 = LD(slc + 2048 + q * 128 + ((16u * g) ^ swz));
        const f16x8 bl1 = LD(slc + 2048 + q * 128 + ((16u * g + 64u) ^ swz));
        __syncthreads();   // all slices read; stage region may now be overwritten

        // ---- prologue: stage tile 0 into buf 0 ----
#pragma unroll
        for (int j = 0; j < 6; ++j) gload16(abase[j] + srcoff[j], lbase[0][j]);
        __syncthreads();   // drains vmcnt(0)

        float m = -1e30f, lsum = 0.f;
        f32x4 Oa[4] = {{0, 0, 0, 0}, {0, 0, 0, 0}, {0, 0, 0, 0}, {0, 0, 0, 0}};

#pragma unroll 1
        for (int t = 0; t < NT; ++t) {
            const int buf = t & 1;
            // ---- prefetch next tile into other buffer ----
            if (t < NT - 1) {
                int tb = (t + 1) * (TS * SZ);
#pragma unroll
                for (int j = 0; j < 6; ++j) gload16(abase[j] + tb + srcoff[j], lbase[buf ^ 1][j]);
            }
            const char* sH = (const char*)&stage[buf][0][0];
            const char* sL = (const char*)&stage[buf][1][0];
            const char* sT = (const char*)&stage[buf][2][0];
            // ---- S^T = sup_tile . h (3-product split) ----
            f32x4 sv[4];
#pragma unroll
            for (int sub = 0; sub < 4; ++sub) {
                u32 rb = (u32)(16 * sub + q) * 128;
                f16x8 aH0 = LD(sH + rb + ((16u * g) ^ swz));
                f16x8 aH1 = LD(sH + rb + ((16u * g + 64u) ^ swz));
                f16x8 aL0 = LD(sL + rb + ((16u * g) ^ swz));
                f16x8 aL1 = LD(sL + rb + ((16u * g + 64u) ^ swz));
                f32x4 a = {0, 0, 0, 0};
                a = MMH(aH0, bh0, a); a = MMH(aH1, bh1, a);
                a = MMH(aH0, bl0, a); a = MMH(aH1, bl1, a);
                a = MMH(aL0, bh0, a); a = MMH(aL1, bh1, a);
                sv[sub] = a;
            }
            // ---- online softmax ----
            float tm = -1e30f;
#pragma unroll
            for (int sub = 0; sub < 4; ++sub)
                tm = fmaxf(tm, fmaxf(fmaxf(sv[sub][0], sv[sub][1]), fmaxf(sv[sub][2], sv[sub][3])));
            tm = fmaxf(tm, __shfl_xor(tm, 16));
            tm = fmaxf(tm, __shfl_xor(tm, 32));
            float mn = fmaxf(m, tm);
            float sc = ex2((m - mn) * L2E);
            m = mn;
            float mL = mn * L2E;
            lsum *= sc;
            Oa[0] *= sc; Oa[1] *= sc; Oa[2] *= sc; Oa[3] *= sc;
            // ---- P = exp(S - m) -> f16 -> swizzled wave-private P_lds ----
            char* pw = (char*)&P_lds[wq][0];
#pragma unroll
            for (int sub = 0; sub < 4; ++sub) {
                float p0 = ex2(sv[sub][0] * L2E - mL);
                float p1 = ex2(sv[sub][1] * L2E - mL);
                float p2 = ex2(sv[sub][2] * L2E - mL);
                float p3 = ex2(sv[sub][3] * L2E - mL);
                lsum += (p0 + p1) + (p2 + p3);
                uint2 w; w.x = pk2(p0, p1); w.y = pk2(p2, p3);
                *(uint2*)(pw + q * 128 + ((32u * sub + 8u * g) ^ swz)) = w;
            }
            lds_fence();
            // ---- O^T += supT_tile . P ----
#pragma unroll
            for (int c4 = 0; c4 < 2; ++c4) {
                u32 kb = (16u * g + 64u * c4) ^ swz;
                f16x8 pb = LD(pw + q * 128 + kb);
#pragma unroll
                for (int dsub = 0; dsub < 4; ++dsub) {
                    f16x8 aT = LD(sT + (u32)(16 * dsub + q) * 128 + kb);
                    Oa[dsub] = MMH(aT, pb, Oa[dsub]);
                }
            }
            __syncthreads();   // drains vmcnt(0): prefetched tile landed; buf swap safe
        }
        lsum += __shfl_xor(lsum, 16);
        lsum += __shfl_xor(lsum, 32);
        float inv = rcp_(lsum);

        // ---- hr = h + readout, hi/lo -> wave slice -> B-frags (stage region idle) ----
#pragma unroll
        for (int s4 = 0; s4 < 4; ++s4) {
            float r0 = hh[4 * s4 + 0] + qv[4 * s4 + 0] + Oa[s4][0] * inv;
            float r1 = hh[4 * s4 + 1] + qv[4 * s4 + 1] + Oa[s4][1] * inv;
            float r2 = hh[4 * s4 + 2] + qv[4 * s4 + 2] + Oa[s4][2] * inv;
            float r3 = hh[4 * s4 + 3] + qv[4 * s4 + 3] + Oa[s4][3] * inv;
            _Float16 a0 = (_Float16)r0, a1 = (_Float16)r1, a2 = (_Float16)r2, a3 = (_Float16)r3;
            uint2 whi, wlo;
            whi.x = (u32)hbits(a0) | ((u32)hbits(a1) << 16);
            whi.y = (u32)hbits(a2) | ((u32)hbits(a3) << 16);
            wlo.x = pk2(r0 - (float)a0, r1 - (float)a1);
            wlo.y = pk2(r2 - (float)a2, r3 - (float)a3);
            u32 b = q * 128 + ((32u * s4 + 8u * g) ^ swz);
            *(uint2*)(slc + b) = whi;
            *(uint2*)(slc + 2048 + b) = wlo;
        }
        lds_fence();
        const f16x8 rh0 = LD(slc + q * 128 + ((16u * g) ^ swz));
        const f16x8 rh1 = LD(slc + q * 128 + ((16u * g + 64u) ^ swz));
        const f16x8 rl0 = LD(slc + 2048 + q * 128 + ((16u * g) ^ swz));
        const f16x8 rl1 = LD(slc + 2048 + q * 128 + ((16u * g + 64u) ^ swz));

        // ---- gates^T = Wstack . [queries; hr] + bias (3-product splits); LSTM ----
#pragma unroll
        for (int s4 = 0; s4 < 4; ++s4) {
            f32x4 ga[4];
#pragma unroll
            for (int ch = 0; ch < 4; ++ch) {  // 0=i 1=f 2=g 3=o
                int u_ = 4 * ch + s4;
                f32x4 a = *(const f32x4*)&bs_lds[16 * u_ + 4 * g];
                const u16* wiH = WiH + (16 * u_ + q) * SZ + 8 * g;
                const u16* wiL = WiL + (16 * u_ + q) * SZ + 8 * g;
                const u16* whH = WhH + (16 * u_ + q) * SZ + 8 * g;
                const u16* whL = WhL + (16 * u_ + q) * SZ + 8 * g;
                f16x8 w0 = LD(wiH), w1 = LD(wiH + 32);
                a = MMH(w0, qfh0, a); a = MMH(w1, qfh1, a);
                a = MMH(w0, qfl0, a); a = MMH(w1, qfl1, a);
                a = MMH(LD(wiL), qfh0, a); a = MMH(LD(wiL + 32), qfh1, a);
                f16x8 v0 = LD(whH), v1 = LD(whH + 32);
                a = MMH(v0, rh0, a); a = MMH(v1, rh1, a);
                a = MMH(v0, rl0, a); a = MMH(v1, rl1, a);
                a = MMH(LD(whL), rh0, a); a = MMH(LD(whL + 32), rh1, a);
                ga[ch] = a;
            }
#pragma unroll
            for (int jj = 0; jj < 4; ++jj) {
                int tt = 4 * s4 + jj;
                float gi = sig(ga[0][jj]);
                float gf = sig(ga[1][jj]);
                float gg = tanh_(ga[2][jj]);
                float go = sig(ga[3][jj]);
                float cn = gf * cc[tt] + gi * gg;
                cc[tt] = cn;
                hh[tt] = go * tanh_(cn);
            }
        }
    }

    // ---- out = h_hat + queries ----
#pragma unroll
    for (int s4 = 0; s4 < 4; ++s4) {
        f32x4 v;
#pragma unroll
        for (int jj = 0; jj < 4; ++jj) v[jj] = hh[4 * s4 + jj] + qv[4 * s4 + jj];
        *(f32x4*)&out[qrow * SZ + 16 * s4 + 4 * g] = v;
    }
}

extern "C" void kernel_launch(void* const* d_in, const int* in_sizes, int n_in,
                              void* d_out, int out_size, void* d_ws, size_t ws_size,
                              hipStream_t stream) {
    const float* support = (const float*)d_in[0];
    const float* queries = (const float*)d_in[1];
    const float* W_ih = (const float*)d_in[2];
    const float* W_hh = (const float*)d_in[3];
    const float* b_ih = (const float*)d_in[4];
    const float* b_hh = (const float*)d_in[5];
    float* out = (float*)d_out;

    u16* supH = (u16*)d_ws;                    // 8192*64
    u16* supL = supH + NS * SZ;                // 8192*64
    u16* supT = supL + NS * SZ;                // 8192*64 (tiled transpose, hi)
    u16* WiH = supT + NS * SZ;                 // 256*64
    u16* WiL = WiH + 4 * SZ * SZ;
    u16* WhH = WiL + 4 * SZ * SZ;
    u16* WhL = WhH + 4 * SZ * SZ;
    float* bs = (float*)(WhL + 4 * SZ * SZ);   // 256

    prep_kernel<<<(NS * SZ) / 256, 256, 0, stream>>>(support, W_ih, W_hh, b_ih, b_hh,
                                                     supH, supL, supT, WiH, WiL, WhH, WhL, bs);
    attlstm_kernel<<<NQ / 64, 256, 0, stream>>>(queries, supH, supL, supT,
                                                WiH, WiL, WhH, WhL, bs, out);
}

// Round 5
// 1434.849 us; speedup vs baseline: 2.6422x; 1.2289x over previous
//
#include <hip/hip_runtime.h>

using u16 = unsigned short;
using u32 = unsigned int;

#define NS 8192
#define NQ 16384
#define SZ 64
#define STEPS 10
#define TS 64
#define TSZ (TS * SZ)      // 4096 elems per tile per array
#define NT (NS / TS)       // 128 tiles
#define NR (NT / 2)        // 64 rounds (2 tiles per round)
#define L2E 1.44269504088896340736f

typedef __attribute__((ext_vector_type(8))) _Float16 f16x8;
typedef __attribute__((ext_vector_type(4))) float f32x4;

static __device__ __forceinline__ float ex2(float x) { float r; asm("v_exp_f32 %0, %1" : "=v"(r) : "v"(x)); return r; }
static __device__ __forceinline__ float rcp_(float x) { float r; asm("v_rcp_f32 %0, %1" : "=v"(r) : "v"(x)); return r; }

static __device__ __forceinline__ u16 hbits(_Float16 h) { union { _Float16 h; u16 u; } c; c.h = h; return c.u; }
static __device__ __forceinline__ u32 pk2(float lo, float hi) {
    return (u32)hbits((_Float16)lo) | ((u32)hbits((_Float16)hi) << 16);
}
static __device__ __forceinline__ f32x4 MMH(f16x8 a, f16x8 b, f32x4 c) {
    return __builtin_amdgcn_mfma_f32_16x16x32_f16(a, b, c, 0, 0, 0);
}
static __device__ __forceinline__ f16x8 LD(const void* p) { return *(const f16x8*)p; }
static __device__ __forceinline__ float sig(float x) { return rcp_(1.f + ex2(-L2E * x)); }
static __device__ __forceinline__ float tanh_(float x) {
    float e = ex2(-2.f * L2E * x);
    return (1.f - e) * rcp_(1.f + e);
}
// wave-local LDS write->read ordering (rule #18)
static __device__ __forceinline__ void lds_fence() {
    asm volatile("s_waitcnt lgkmcnt(0)" ::: "memory");
    __builtin_amdgcn_sched_barrier(0);
}
// async global->LDS, 16B/lane, LDS dest wave-uniform + lane*16
static __device__ __forceinline__ void gload16(const void* g, void* l) {
    __builtin_amdgcn_global_load_lds(
        (const __attribute__((address_space(1))) void*)g,
        (__attribute__((address_space(3))) void*)l, 16, 0, 0);
}

// ---------------- prep: f16 hi/lo splits + tiled transpose (TS=64) + bias sum ----------------
__global__ void prep_kernel(const float* __restrict__ sup,
                            const float* __restrict__ Wih,
                            const float* __restrict__ Whh,
                            const float* __restrict__ bih,
                            const float* __restrict__ bhh,
                            u16* __restrict__ supH, u16* __restrict__ supL,
                            u16* __restrict__ supT,
                            u16* __restrict__ WiH, u16* __restrict__ WiL,
                            u16* __restrict__ WhH, u16* __restrict__ WhL,
                            float* __restrict__ bs) {
    int i = blockIdx.x * 256 + threadIdx.x;
    if (i < NS * SZ) {
        float v = sup[i];
        _Float16 hi = (_Float16)v;
        _Float16 lo = (_Float16)(v - (float)hi);
        supH[i] = hbits(hi);
        supL[i] = hbits(lo);
        int s = i >> 6, d = i & 63;
        supT[(s >> 6) * TSZ + d * TS + (s & 63)] = hbits(hi);
    }
    if (i < 4 * SZ * SZ) {
        float a = Wih[i]; _Float16 ah = (_Float16)a;
        WiH[i] = hbits(ah); WiL[i] = hbits((_Float16)(a - (float)ah));
        float b = Whh[i]; _Float16 bh = (_Float16)b;
        WhH[i] = hbits(bh); WhL[i] = hbits((_Float16)(b - (float)bh));
    }
    if (i < 4 * SZ) bs[i] = bih[i] + bhh[i];
}

// ---------------- main kernel: 8 waves/block, 2-way split-K over support tiles ----------------
// Waves w and w+4 share query group wq=w&3 (16 queries); w<4 = even tile of each
// round pair, w>=4 = odd tile. Lead waves (w<4) own gates/LSTM/output; merge of
// online-softmax state (m, lsum, Oa) once per step via LDS (exact in f32).
__global__ __launch_bounds__(512, 2) void attlstm_kernel(
    const float* __restrict__ queries,
    const u16* __restrict__ supH, const u16* __restrict__ supL,
    const u16* __restrict__ supT,
    const u16* __restrict__ WiH, const u16* __restrict__ WiL,
    const u16* __restrict__ WhH, const u16* __restrict__ WhL,
    const float* __restrict__ bsum,
    float* __restrict__ out) {
    __shared__ __align__(16) u16 stage[4][3][TSZ];   // 96KB: 4 tile-bufs x {supH,supL,supT}
    __shared__ __align__(16) u32 P_lds[8][512];      // 16KB: per-wave P, swizzled
    __shared__ __align__(16) u16 hsl[4][2048];       // 16KB: per-qgroup h hi[0..1023]/lo[1024..]
    __shared__ __align__(16) float bs_lds[256];      // 1KB

    const int tid = threadIdx.x;
    const int w = tid >> 6;
    const int l = tid & 63;
    const int wq = w & 3;
    const int half = w >> 2;
    const int q = l & 15;
    const int g = l >> 4;
    const int qrow = blockIdx.x * 64 + wq * 16 + q;
    const u32 swz = (u32)(q & 7) << 4;
    const bool lead = (half == 0);

    if (tid < 256) bs_lds[tid] = bsum[tid];

    // staging: wave w stages sub-block s8=w (8 rows) of each array, both tiles of the pair
    const int srcoff = (w * 8 + (l >> 3)) * SZ + ((l & 7) ^ (l >> 3)) * 8;
    const u16* abase[3] = {supH, supL, supT};
    char* hslb = (char*)&hsl[wq][0];
    char* pw = (char*)&P_lds[w][0];

    float qv[16], hh[16], cc[16];
    f16x8 qfh0, qfh1, qfl0, qfl1;
    if (lead) {
#pragma unroll
        for (int s4 = 0; s4 < 4; ++s4) {
            f32x4 v = *(const f32x4*)&queries[qrow * SZ + 16 * s4 + 4 * g];
#pragma unroll
            for (int jj = 0; jj < 4; ++jj) {
                qv[4 * s4 + jj] = v[jj];
                hh[4 * s4 + jj] = 0.f;
                cc[4 * s4 + jj] = 0.f;
            }
            _Float16 c0 = (_Float16)v[0], c1 = (_Float16)v[1], c2 = (_Float16)v[2], c3 = (_Float16)v[3];
            uint2 whi, wlo;
            whi.x = (u32)hbits(c0) | ((u32)hbits(c1) << 16);
            whi.y = (u32)hbits(c2) | ((u32)hbits(c3) << 16);
            wlo.x = pk2(v[0] - (float)c0, v[1] - (float)c1);
            wlo.y = pk2(v[2] - (float)c2, v[3] - (float)c3);
            u32 b = q * 128 + ((32u * s4 + 8u * g) ^ swz);
            *(uint2*)(hslb + b) = whi;
            *(uint2*)(hslb + 2048 + b) = wlo;
        }
        lds_fence();
        qfh0 = LD(hslb + q * 128 + ((16u * g) ^ swz));
        qfh1 = LD(hslb + q * 128 + ((16u * g + 64u) ^ swz));
        qfl0 = LD(hslb + 2048 + q * 128 + ((16u * g) ^ swz));
        qfl1 = LD(hslb + 2048 + q * 128 + ((16u * g + 64u) ^ swz));
    }

#pragma unroll 1
    for (int step = 0; step < STEPS; ++step) {
        // ---- lead: h = h_hat + queries, hi/lo -> hsl[wq] ----
        if (lead) {
#pragma unroll
            for (int s4 = 0; s4 < 4; ++s4) {
                float h0 = hh[4 * s4 + 0] + qv[4 * s4 + 0];
                float h1 = hh[4 * s4 + 1] + qv[4 * s4 + 1];
                float h2 = hh[4 * s4 + 2] + qv[4 * s4 + 2];
                float h3 = hh[4 * s4 + 3] + qv[4 * s4 + 3];
                _Float16 a0 = (_Float16)h0, a1 = (_Float16)h1, a2 = (_Float16)h2, a3 = (_Float16)h3;
                uint2 whi, wlo;
                whi.x = (u32)hbits(a0) | ((u32)hbits(a1) << 16);
                whi.y = (u32)hbits(a2) | ((u32)hbits(a3) << 16);
                wlo.x = pk2(h0 - (float)a0, h1 - (float)a1);
                wlo.y = pk2(h2 - (float)a2, h3 - (float)a3);
                u32 b = q * 128 + ((32u * s4 + 8u * g) ^ swz);
                *(uint2*)(hslb + b) = whi;
                *(uint2*)(hslb + 2048 + b) = wlo;
            }
        }
        __syncthreads();
        const f16x8 bh0 = LD(hslb + q * 128 + ((16u * g) ^ swz));
        const f16x8 bh1 = LD(hslb + q * 128 + ((16u * g + 64u) ^ swz));
        const f16x8 bl0 = LD(hslb + 2048 + q * 128 + ((16u * g) ^ swz));
        const f16x8 bl1 = LD(hslb + 2048 + q * 128 + ((16u * g + 64u) ^ swz));

        // ---- prologue: stage tiles 0,1 into bufs 0,1 ----
#pragma unroll
        for (int a = 0; a < 3; ++a) {
            gload16(abase[a] + 0 * TSZ + srcoff, &stage[0][a][w * 512]);
            gload16(abase[a] + 1 * TSZ + srcoff, &stage[1][a][w * 512]);
        }
        __syncthreads();

        float m = -1e30f, mL = -1.5e30f, lsum = 0.f;
        f32x4 Oa[4] = {{0, 0, 0, 0}, {0, 0, 0, 0}, {0, 0, 0, 0}, {0, 0, 0, 0}};

#pragma unroll 1
        for (int r = 0; r < NR; ++r) {
            const int bufc = (2 * r + half) & 3;
            // ---- prefetch next round's pair ----
            if (r < NR - 1) {
                const int tA = 2 * r + 2, tB = 2 * r + 3;
#pragma unroll
                for (int a = 0; a < 3; ++a) {
                    gload16(abase[a] + tA * TSZ + srcoff, &stage[tA & 3][a][w * 512]);
                    gload16(abase[a] + tB * TSZ + srcoff, &stage[tB & 3][a][w * 512]);
                }
            }
            const char* sH = (const char*)&stage[bufc][0][0];
            const char* sL = (const char*)&stage[bufc][1][0];
            const char* sT = (const char*)&stage[bufc][2][0];
            // ---- S^T = sup_tile . h (3-product hi/lo split) ----
            f32x4 sv[4];
#pragma unroll
            for (int sub = 0; sub < 4; ++sub) {
                u32 rb = (u32)(16 * sub + q) * 128;
                f16x8 aH0 = LD(sH + rb + ((16u * g) ^ swz));
                f16x8 aH1 = LD(sH + rb + ((16u * g + 64u) ^ swz));
                f16x8 aL0 = LD(sL + rb + ((16u * g) ^ swz));
                f16x8 aL1 = LD(sL + rb + ((16u * g + 64u) ^ swz));
                f32x4 a = {0, 0, 0, 0};
                a = MMH(aH0, bh0, a); a = MMH(aH1, bh1, a);
                a = MMH(aH0, bl0, a); a = MMH(aH1, bl1, a);
                a = MMH(aL0, bh0, a); a = MMH(aL1, bh1, a);
                sv[sub] = a;
            }
            // ---- online softmax with defer-max (T13) ----
            float tm = -1e30f;
#pragma unroll
            for (int sub = 0; sub < 4; ++sub)
                tm = fmaxf(tm, fmaxf(fmaxf(sv[sub][0], sv[sub][1]), fmaxf(sv[sub][2], sv[sub][3])));
            tm = fmaxf(tm, __shfl_xor(tm, 16));
            tm = fmaxf(tm, __shfl_xor(tm, 32));
            if (__any(tm > m + 5.5f)) {
                float mn = fmaxf(m, tm);
                float sc = ex2((m - mn) * L2E);
                lsum *= sc;
                Oa[0] *= sc; Oa[1] *= sc; Oa[2] *= sc; Oa[3] *= sc;
                m = mn; mL = m * L2E;
            }
            // ---- P = exp(S - m) -> f16 -> swizzled per-wave P_lds ----
#pragma unroll
            for (int sub = 0; sub < 4; ++sub) {
                float p0 = ex2(sv[sub][0] * L2E - mL);
                float p1 = ex2(sv[sub][1] * L2E - mL);
                float p2 = ex2(sv[sub][2] * L2E - mL);
                float p3 = ex2(sv[sub][3] * L2E - mL);
                lsum += (p0 + p1) + (p2 + p3);
                uint2 wv; wv.x = pk2(p0, p1); wv.y = pk2(p2, p3);
                *(uint2*)(pw + q * 128 + ((32u * sub + 8u * g) ^ swz)) = wv;
            }
            lds_fence();
            // ---- O^T += supT_tile . P ----
#pragma unroll
            for (int c4 = 0; c4 < 2; ++c4) {
                u32 kb = (16u * g + 64u * c4) ^ swz;
                f16x8 pb = LD(pw + q * 128 + kb);
#pragma unroll
                for (int dsub = 0; dsub < 4; ++dsub) {
                    f16x8 aT = LD(sT + (u32)(16 * dsub + q) * 128 + kb);
                    Oa[dsub] = MMH(aT, pb, Oa[dsub]);
                }
            }
            __syncthreads();   // drains vmcnt(0): next pair staged; bufs rotate
        }
        lsum += __shfl_xor(lsum, 16);
        lsum += __shfl_xor(lsum, 32);

        // ---- merge split-K halves (scratch aliases stage; barrier-separated) ----
        float* mg = (float*)&stage[0][0][0];
        float* mine = mg + (u32)(w * 64 + l) * 20;
        *(f32x4*)(mine + 0) = Oa[0];
        *(f32x4*)(mine + 4) = Oa[1];
        *(f32x4*)(mine + 8) = Oa[2];
        *(f32x4*)(mine + 12) = Oa[3];
        mine[16] = m; mine[17] = lsum;
        __syncthreads();

        if (lead) {
            const float* oth = mg + (u32)((w + 4) * 64 + l) * 20;
            f32x4 Ob0 = *(const f32x4*)(oth + 0);
            f32x4 Ob1 = *(const f32x4*)(oth + 4);
            f32x4 Ob2 = *(const f32x4*)(oth + 8);
            f32x4 Ob3 = *(const f32x4*)(oth + 12);
            float mo = oth[16], lo_ = oth[17];
            float M = fmaxf(m, mo);
            float sA = ex2((m - M) * L2E), sB = ex2((mo - M) * L2E);
            lsum = lsum * sA + lo_ * sB;
            Oa[0] = Oa[0] * sA + Ob0 * sB;
            Oa[1] = Oa[1] * sA + Ob1 * sB;
            Oa[2] = Oa[2] * sA + Ob2 * sB;
            Oa[3] = Oa[3] * sA + Ob3 * sB;
            float inv = rcp_(lsum);

            // ---- hr = h + readout, hi/lo -> hsl[wq] (wave-local round-trip) ----
#pragma unroll
            for (int s4 = 0; s4 < 4; ++s4) {
                float r0 = hh[4 * s4 + 0] + qv[4 * s4 + 0] + Oa[s4][0] * inv;
                float r1 = hh[4 * s4 + 1] + qv[4 * s4 + 1] + Oa[s4][1] * inv;
                float r2 = hh[4 * s4 + 2] + qv[4 * s4 + 2] + Oa[s4][2] * inv;
                float r3 = hh[4 * s4 + 3] + qv[4 * s4 + 3] + Oa[s4][3] * inv;
                _Float16 a0 = (_Float16)r0, a1 = (_Float16)r1, a2 = (_Float16)r2, a3 = (_Float16)r3;
                uint2 whi, wlo;
                whi.x = (u32)hbits(a0) | ((u32)hbits(a1) << 16);
                whi.y = (u32)hbits(a2) | ((u32)hbits(a3) << 16);
                wlo.x = pk2(r0 - (float)a0, r1 - (float)a1);
                wlo.y = pk2(r2 - (float)a2, r3 - (float)a3);
                u32 b = q * 128 + ((32u * s4 + 8u * g) ^ swz);
                *(uint2*)(hslb + b) = whi;
                *(uint2*)(hslb + 2048 + b) = wlo;
            }
            lds_fence();
            const f16x8 rh0 = LD(hslb + q * 128 + ((16u * g) ^ swz));
            const f16x8 rh1 = LD(hslb + q * 128 + ((16u * g + 64u) ^ swz));
            const f16x8 rl0 = LD(hslb + 2048 + q * 128 + ((16u * g) ^ swz));
            const f16x8 rl1 = LD(hslb + 2048 + q * 128 + ((16u * g + 64u) ^ swz));

            // ---- gates^T = Wstack . [queries; hr] + bias; LSTM elementwise ----
#pragma unroll
            for (int s4 = 0; s4 < 4; ++s4) {
                f32x4 ga[4];
#pragma unroll
                for (int ch = 0; ch < 4; ++ch) {  // 0=i 1=f 2=g 3=o
                    int u_ = 4 * ch + s4;
                    f32x4 a = *(const f32x4*)&bs_lds[16 * u_ + 4 * g];
                    const u16* wiH = WiH + (16 * u_ + q) * SZ + 8 * g;
                    const u16* wiL = WiL + (16 * u_ + q) * SZ + 8 * g;
                    const u16* whH = WhH + (16 * u_ + q) * SZ + 8 * g;
                    const u16* whL = WhL + (16 * u_ + q) * SZ + 8 * g;
                    f16x8 w0 = LD(wiH), w1 = LD(wiH + 32);
                    a = MMH(w0, qfh0, a); a = MMH(w1, qfh1, a);
                    a = MMH(w0, qfl0, a); a = MMH(w1, qfl1, a);
                    a = MMH(LD(wiL), qfh0, a); a = MMH(LD(wiL + 32), qfh1, a);
                    f16x8 v0 = LD(whH), v1 = LD(whH + 32);
                    a = MMH(v0, rh0, a); a = MMH(v1, rh1, a);
                    a = MMH(v0, rl0, a); a = MMH(v1, rl1, a);
                    a = MMH(LD(whL), rh0, a); a = MMH(LD(whL + 32), rh1, a);
                    ga[ch] = a;
                }
#pragma unroll
                for (int jj = 0; jj < 4; ++jj) {
                    int tt = 4 * s4 + jj;
                    float gi = sig(ga[0][jj]);
                    float gf = sig(ga[1][jj]);
                    float gg = tanh_(ga[2][jj]);
                    float go = sig(ga[3][jj]);
                    float cn = gf * cc[tt] + gi * gg;
                    cc[tt] = cn;
                    hh[tt] = go * tanh_(cn);
                }
            }
        }
    }

    // ---- out = h_hat + queries (lead only) ----
    if (lead) {
#pragma unroll
        for (int s4 = 0; s4 < 4; ++s4) {
            f32x4 v;
#pragma unroll
            for (int jj = 0; jj < 4; ++jj) v[jj] = hh[4 * s4 + jj] + qv[4 * s4 + jj];
            *(f32x4*)&out[qrow * SZ + 16 * s4 + 4 * g] = v;
        }
    }
}

extern "C" void kernel_launch(void* const* d_in, const int* in_sizes, int n_in,
                              void* d_out, int out_size, void* d_ws, size_t ws_size,
                              hipStream_t stream) {
    const float* support = (const float*)d_in[0];
    const float* queries = (const float*)d_in[1];
    const float* W_ih = (const float*)d_in[2];
    const float* W_hh = (const float*)d_in[3];
    const float* b_ih = (const float*)d_in[4];
    const float* b_hh = (const float*)d_in[5];
    float* out = (float*)d_out;

    u16* supH = (u16*)d_ws;                    // 8192*64
    u16* supL = supH + NS * SZ;                // 8192*64
    u16* supT = supL + NS * SZ;                // 8192*64 (tiled transpose, hi)
    u16* WiH = supT + NS * SZ;                 // 256*64
    u16* WiL = WiH + 4 * SZ * SZ;
    u16* WhH = WiL + 4 * SZ * SZ;
    u16* WhL = WhH + 4 * SZ * SZ;
    float* bs = (float*)(WhL + 4 * SZ * SZ);   // 256

    prep_kernel<<<(NS * SZ) / 256, 256, 0, stream>>>(support, W_ih, W_hh, b_ih, b_hh,
                                                     supH, supL, supT, WiH, WiL, WhH, WhL, bs);
    attlstm_kernel<<<NQ / 64, 512, 0, stream>>>(queries, supH, supL, supT,
                                                WiH, WiL, WhH, WhL, bs, out);
}